// Round 1
// 458.761 us; speedup vs baseline: 1.0071x; 1.0071x over previous
//
#include <hip/hip_runtime.h>
#include <stdint.h>

typedef unsigned short u16;
typedef short bf16x8 __attribute__((ext_vector_type(8)));
typedef float f32x4 __attribute__((ext_vector_type(4)));
typedef u16 u16x8 __attribute__((ext_vector_type(8)));
typedef u16 u16x4v __attribute__((ext_vector_type(4)));

#define EMBED 512
#define NBATCH 8
#define QLEN 2048
#define KLEN 4096

__device__ __forceinline__ u16 f2bf(float f) {
  uint32_t u = __builtin_bit_cast(uint32_t, f);
  u += 0x7fffu + ((u >> 16) & 1u);   // RNE
  return (u16)(u >> 16);
}
__device__ __forceinline__ float bf2f(u16 b) {
  return __builtin_bit_cast(float, (uint32_t)b << 16);
}

// async global->LDS, 16B per lane. LDS dest = wave-uniform base + lane*16 (linear).
__device__ __forceinline__ void gload_lds16(const void* g, void* lds) {
  __builtin_amdgcn_global_load_lds(
      (__attribute__((address_space(1))) void*)(uintptr_t)g,
      (__attribute__((address_space(3))) void*)(uint32_t)(uintptr_t)lds,
      16, 0, 0);
}

// one kernel converts all six fp32 inputs into the contiguous bf16 region at
// the start of ws (layout: xb | yb | Wqb | Wkb | Wvb | Wob)
__global__ __launch_bounds__(256) void cvt_all_kernel(
    const float* __restrict__ x, const float* __restrict__ y,
    const float* __restrict__ wq, const float* __restrict__ wk,
    const float* __restrict__ wv, const float* __restrict__ wo,
    u16* __restrict__ dst) {
  const int64_t B0 = 2097152;        // nx/4
  const int64_t B1 = B0 + 4194304;   // + ny/4
  const int64_t B2 = B1 + 65536;
  const int64_t B3 = B2 + 65536;
  const int64_t B4 = B3 + 65536;
  int64_t i = (int64_t)blockIdx.x * 256 + threadIdx.x;  // float4 units
  const float* src; int64_t off;
  if (i < B0)      { src = x;  off = 0;  }
  else if (i < B1) { src = y;  off = B0; }
  else if (i < B2) { src = wq; off = B1; }
  else if (i < B3) { src = wk; off = B2; }
  else if (i < B4) { src = wv; off = B3; }
  else             { src = wo; off = B4; }
  float4 f = ((const float4*)src)[i - off];
  u16x4v o = { f2bf(f.x), f2bf(f.y), f2bf(f.z), f2bf(f.w) };
  ((u16x4v*)dst)[i] = o;
}

// ---------------------------------------------------------------------------
// Generic C = A * B^T   (A: MxK bf16 row-major, B: NxK bf16 row-major)
// 128x128 tile, BK=64, 4 waves (each 64x64), mfma_f32_16x16x32_bf16.
// ---------------------------------------------------------------------------
constexpr int EPI_BF16 = 0;        // C bf16 [M][N]
constexpr int EPI_BF16_SCALE = 1;  // C bf16 = acc*scale
constexpr int EPI_BF16_TRANS = 2;  // Vt[nb][d=col][k=row%4096] bf16
constexpr int EPI_F32_RESID = 3;   // C f32 = acc + xres + bias[col]

template <int MODE>
__global__ __launch_bounds__(256, 2) void gemm_bt(
    const u16* __restrict__ A, const u16* __restrict__ B, void* __restrict__ Cv,
    int M, int N, int K,
    int64_t aBatch, int64_t bBatch, int64_t cBatch,
    float scale, const float* __restrict__ xres, const float* __restrict__ bias,
    u16* __restrict__ Vt) {
  __shared__ __align__(16) u16 As[128 * 64];
  __shared__ __align__(16) u16 Bs[128 * 64];

  const int tid = threadIdx.x;
  const int wave = tid >> 6;
  const int lane = tid & 63;
  const int bz = blockIdx.z;
  const int row0 = blockIdx.x * 128;
  const int col0 = blockIdx.y * 128;
  const u16* Ab = A + (int64_t)bz * aBatch;
  const u16* Bb = B + (int64_t)bz * bBatch;

  const int srow = wave * 32 + (lane >> 3);
  const int scol = (lane & 7) * 8;
  const u16* aSrc = Ab + (int64_t)(row0 + srow) * K + scol;
  const u16* bSrc = Bb + (int64_t)(col0 + srow) * K + scol;

  const int wm = (wave >> 1) * 64;
  const int wn = (wave & 1) * 64;
  const int fr = lane & 15;
  const int fq = lane >> 4;

  f32x4 acc[4][4];
#pragma unroll
  for (int mi = 0; mi < 4; ++mi)
#pragma unroll
    for (int ni = 0; ni < 4; ++ni) acc[mi][ni] = 0.0f;

  const int nkt = K >> 6;
  for (int kt = 0; kt < nkt; ++kt) {
    __syncthreads();
    const u16* aS = aSrc + kt * 64;
    const u16* bS = bSrc + kt * 64;
#pragma unroll
    for (int i = 0; i < 4; ++i) {
      gload_lds16(aS + (int64_t)(i * 8) * K, &As[(wave * 32 + i * 8) * 64]);
      gload_lds16(bS + (int64_t)(i * 8) * K, &Bs[(wave * 32 + i * 8) * 64]);
    }
    __syncthreads();
#pragma unroll
    for (int ks = 0; ks < 2; ++ks) {
      bf16x8 af[4], bfr[4];
#pragma unroll
      for (int mi = 0; mi < 4; ++mi)
        af[mi] = *(const bf16x8*)&As[(wm + mi * 16 + fr) * 64 + ks * 32 + fq * 8];
#pragma unroll
      for (int ni = 0; ni < 4; ++ni)
        bfr[ni] = *(const bf16x8*)&Bs[(wn + ni * 16 + fr) * 64 + ks * 32 + fq * 8];
#pragma unroll
      for (int mi = 0; mi < 4; ++mi)
#pragma unroll
        for (int ni = 0; ni < 4; ++ni)
          acc[mi][ni] = __builtin_amdgcn_mfma_f32_16x16x32_bf16(af[mi], bfr[ni],
                                                                acc[mi][ni], 0, 0, 0);
    }
  }

  // C/D layout: col = lane&15, row = (lane>>4)*4 + reg  [m89-verified]
  if constexpr (MODE == EPI_BF16 || MODE == EPI_BF16_SCALE) {
    u16* C = (u16*)Cv + (int64_t)bz * cBatch;
#pragma unroll
    for (int mi = 0; mi < 4; ++mi) {
      const int rowb = row0 + wm + mi * 16 + fq * 4;
#pragma unroll
      for (int ni = 0; ni < 4; ++ni) {
        const int col = col0 + wn + ni * 16 + fr;
#pragma unroll
        for (int r = 0; r < 4; ++r) {
          float v = acc[mi][ni][r];
          if constexpr (MODE == EPI_BF16_SCALE) v *= scale;
          C[(int64_t)(rowb + r) * N + col] = f2bf(v);
        }
      }
    }
  } else if constexpr (MODE == EPI_BF16_TRANS) {
#pragma unroll
    for (int mi = 0; mi < 4; ++mi) {
      const int rowb = row0 + wm + mi * 16 + fq * 4;
      const int nb = rowb >> 12;
      const int kk = rowb & 4095;
#pragma unroll
      for (int ni = 0; ni < 4; ++ni) {
        const int col = col0 + wn + ni * 16 + fr;
        u16x4v o = { f2bf(acc[mi][ni][0]), f2bf(acc[mi][ni][1]),
                     f2bf(acc[mi][ni][2]), f2bf(acc[mi][ni][3]) };
        *(u16x4v*)&Vt[((int64_t)nb * EMBED + col) * KLEN + kk] = o;
      }
    }
  } else {  // EPI_F32_RESID
    float* C = (float*)Cv;
#pragma unroll
    for (int mi = 0; mi < 4; ++mi) {
      const int rowb = row0 + wm + mi * 16 + fq * 4;
#pragma unroll
      for (int ni = 0; ni < 4; ++ni) {
        const int col = col0 + wn + ni * 16 + fr;
        const float bv = bias[col];
#pragma unroll
        for (int r = 0; r < 4; ++r) {
          const int64_t idx = (int64_t)(rowb + r) * N + col;
          C[idx] = acc[mi][ni][r] + xres[idx] + bv;
        }
      }
    }
  }
}

// ---------------------------------------------------------------------------
// Fused flash attention, pipelined (T3 single-vmcnt-drain + T14 V-in-reg).
// Block = 4 waves, 64 q rows. QK^T: wave w owns q rows w*16..+15 (all keys).
// PV: wave w owns d cols w*128..+127 (all 64 q rows) -> V fragments are
// lane-exact global loads (no LDS). Cross-wave P/alpha via LDS with a raw
// s_barrier (lgkmcnt-only — K prefetch stays in flight across it).
// K tile double-buffered; the only vmcnt(0) drain is iter-end __syncthreads.
//
// T1 (this round): batch->XCD co-location. Blocks sharing a batch's K/V
// stream ~8MB of cache-side reads; with the old decode (nb = blockIdx.x>>5)
// those 32 blocks round-robin across all 8 XCDs, so every XCD streams all
// 8 batches (~32MB) through its 4MB L2 -> near-zero L2 hits, ~2GB served by
// L3 (~5.2 TB/s effective = the measured wall). Decoding nb = blockIdx.x&7
// puts all 32 q-blocks of batch b on XCD b (round-robin dispatch); they
// advance through key-tiles in phase, so the live K/V working set is ~2
// tiles (~64KB) and the 2GB of re-reads become L2 hits.
// ---------------------------------------------------------------------------
__global__ __launch_bounds__(256, 1) void attn_kernel(
    const u16* __restrict__ Qm, const u16* __restrict__ Km,
    const u16* __restrict__ Vt, u16* __restrict__ O) {
  __shared__ __align__(16) u16 Ks[2][32 * 512];  // 2 x 32KB
  __shared__ __align__(16) u16 Ps[64 * 32];      // 4KB, chunk-swizzled
  __shared__ __align__(16) float Als[64];        // per-q-row alpha / final l

  const int tid = threadIdx.x;
  const int w = tid >> 6;
  const int lane = tid & 63;
  const int fr = lane & 15, fq = lane >> 4;
  const int s7 = fr & 7;
  const int nb = blockIdx.x & 7;   // T1: batch -> XCD (round-robin dispatch)
  const int qt = blockIdx.x >> 3;

  // Q fragments: wave w's 16 q rows (A-frag: lane fr = row, fq*8 = k-chunk)
  bf16x8 q[16];
  {
    const u16* Qb = Qm + ((int64_t)nb * QLEN + qt * 64 + w * 16 + fr) * EMBED + fq * 8;
#pragma unroll
    for (int kc = 0; kc < 16; ++kc) q[kc] = *(const bf16x8*)&Qb[kc * 32];
  }

  f32x4 o[32];  // o[mi*8+ni]: q row mi*16+fq*4+r, d col w*128+ni*16+fr
#pragma unroll
  for (int i = 0; i < 32; ++i) o[i] = 0.0f;
  f32x4 mrun, lrun;
#pragma unroll
  for (int r = 0; r < 4; ++r) { mrun[r] = -1e30f; lrun[r] = 0.0f; }

  const u16* Kb = Km + (int64_t)nb * KLEN * EMBED;
  const u16* VbW = Vt + (int64_t)nb * (int64_t)EMBED * KLEN + (int64_t)(w * 128) * KLEN;

  // prologue: stage K tile 0 into slot 0 (swizzle: src chunk = lane ^ (row&7))
  {
    const u16* src = Kb + (int64_t)(w * 8) * EMBED;
#pragma unroll
    for (int i = 0; i < 8; ++i)
      gload_lds16(src + (int64_t)i * EMBED + (lane ^ i) * 8, &Ks[0][(w * 8 + i) * 512]);
  }
  __syncthreads();

  const int NT = KLEN / 32;  // 128
  for (int t = 0; t < NT; ++t) {
    const int cur = t & 1;
    // prefetch K[t+1] into other slot (drained by iter-end __syncthreads)
    if (t + 1 < NT) {
      const u16* src = Kb + ((int64_t)(t + 1) * 32 + w * 8) * EMBED;
#pragma unroll
      for (int i = 0; i < 8; ++i)
        gload_lds16(src + (int64_t)i * EMBED + (lane ^ i) * 8,
                    &Ks[cur ^ 1][(w * 8 + i) * 512]);
    }
    // V fragments for this tile: global -> regs, issued early (T14)
    bf16x8 vf[8];
#pragma unroll
    for (int ni = 0; ni < 8; ++ni)
      vf[ni] = *(const bf16x8*)&VbW[(int64_t)(ni * 16 + fr) * KLEN + t * 32 + fq * 8];

    // S = Q K^T  (16 q rows x 32 keys per wave)
    const u16* Kc = Ks[cur];
    f32x4 s[2];
    s[0] = 0.0f; s[1] = 0.0f;
#pragma unroll
    for (int kc = 0; kc < 16; ++kc) {
#pragma unroll
      for (int ni = 0; ni < 2; ++ni) {
        bf16x8 b = *(const bf16x8*)&Kc[(ni * 16 + fr) * 512 + (((kc * 4 + fq) ^ s7) * 8)];
        s[ni] = __builtin_amdgcn_mfma_f32_16x16x32_bf16(q[kc], b, s[ni], 0, 0, 0);
      }
    }

    // online softmax with defer-max (T13, THR=8)
    f32x4 mt;
#pragma unroll
    for (int r = 0; r < 4; ++r) mt[r] = fmaxf(s[0][r], s[1][r]);
#pragma unroll
    for (int off = 1; off <= 8; off <<= 1)
#pragma unroll
      for (int r = 0; r < 4; ++r) mt[r] = fmaxf(mt[r], __shfl_xor(mt[r], off));
    int ok = 1;
#pragma unroll
    for (int r = 0; r < 4; ++r) ok &= (mt[r] <= mrun[r] + 8.0f);
    f32x4 alpha;
    if (__all(ok)) {
#pragma unroll
      for (int r = 0; r < 4; ++r) alpha[r] = 1.0f;
    } else {
#pragma unroll
      for (int r = 0; r < 4; ++r) {
        float mn = fmaxf(mrun[r], mt[r]);
        alpha[r] = __expf(mrun[r] - mn);
        lrun[r] *= alpha[r];
        mrun[r] = mn;
      }
    }
    float p[2][4];
    f32x4 rs;
#pragma unroll
    for (int r = 0; r < 4; ++r) rs[r] = 0.0f;
#pragma unroll
    for (int ni = 0; ni < 2; ++ni)
#pragma unroll
      for (int r = 0; r < 4; ++r) {
        p[ni][r] = __expf(s[ni][r] - mrun[r]);
        rs[r] += p[ni][r];
      }
#pragma unroll
    for (int off = 1; off <= 8; off <<= 1)
#pragma unroll
      for (int r = 0; r < 4; ++r) rs[r] += __shfl_xor(rs[r], off);
#pragma unroll
    for (int r = 0; r < 4; ++r) lrun[r] += rs[r];

    // P -> LDS. Swizzle: phys_chunk = logical ^ (row&3) ^ ((row>>2)&3);
    // write row = w*16+fq*4+r -> row&3=r, (row>>2)&3=fq.
#pragma unroll
    for (int ni = 0; ni < 2; ++ni)
#pragma unroll
      for (int r = 0; r < 4; ++r)
        Ps[(w * 16 + fq * 4 + r) * 32 + (((ni * 2 + (fr >> 3)) ^ r ^ fq) * 8) + (fr & 7)]
            = f2bf(p[ni][r]);
    if (fr == 0) {
#pragma unroll
      for (int r = 0; r < 4; ++r) Als[w * 16 + fq * 4 + r] = alpha[r];
    }

    // P/alpha visible to all waves WITHOUT draining vmcnt (prefetch in flight)
    asm volatile("s_waitcnt lgkmcnt(0)" ::: "memory");
    __builtin_amdgcn_sched_barrier(0);
    __builtin_amdgcn_s_barrier();
    __builtin_amdgcn_sched_barrier(0);

    // rescale o by cross-wave alphas (skipped when all alpha == 1)
    f32x4 ra[4];
#pragma unroll
    for (int mi = 0; mi < 4; ++mi) ra[mi] = *(const f32x4*)&Als[mi * 16 + fq * 4];
    int nz = 0;
#pragma unroll
    for (int mi = 0; mi < 4; ++mi)
#pragma unroll
      for (int r = 0; r < 4; ++r) nz |= (ra[mi][r] != 1.0f);
    if (__any(nz)) {
#pragma unroll
      for (int mi = 0; mi < 4; ++mi)
#pragma unroll
        for (int ni = 0; ni < 8; ++ni)
#pragma unroll
          for (int r = 0; r < 4; ++r) o[mi * 8 + ni][r] *= ra[mi][r];
    }

    // PV: A-frag row = mi*16+fr -> row&3=fr&3, (row>>2)&3=(fr>>2)&3
    bf16x8 ap[4];
#pragma unroll
    for (int mi = 0; mi < 4; ++mi)
      ap[mi] = *(const bf16x8*)&Ps[(mi * 16 + fr) * 32 +
                                   ((fq ^ (fr & 3) ^ ((fr >> 2) & 3)) * 8)];
#pragma unroll
    for (int mi = 0; mi < 4; ++mi)
#pragma unroll
      for (int ni = 0; ni < 8; ++ni)
        o[mi * 8 + ni] = __builtin_amdgcn_mfma_f32_16x16x32_bf16(ap[mi], vf[ni],
                                                                 o[mi * 8 + ni], 0, 0, 0);

    __syncthreads();  // single vmcnt(0) drain: K prefetch landed; Ps/Ks safe
  }

  // share l across waves, normalize, store
  if (fr == 0) {
#pragma unroll
    for (int r = 0; r < 4; ++r) Als[w * 16 + fq * 4 + r] = lrun[r];
  }
  __syncthreads();
  f32x4 li[4];
#pragma unroll
  for (int mi = 0; mi < 4; ++mi) {
    f32x4 lv = *(const f32x4*)&Als[mi * 16 + fq * 4];
#pragma unroll
    for (int r = 0; r < 4; ++r) li[mi][r] = 1.0f / lv[r];
  }
  u16* Ob = O + ((int64_t)nb * QLEN + qt * 64) * EMBED + w * 128;
#pragma unroll
  for (int mi = 0; mi < 4; ++mi)
#pragma unroll
    for (int ni = 0; ni < 8; ++ni)
#pragma unroll
      for (int r = 0; r < 4; ++r)
        Ob[(int64_t)(mi * 16 + fq * 4 + r) * EMBED + ni * 16 + fr] =
            f2bf(o[mi * 8 + ni][r] * li[mi][r]);
}

extern "C" void kernel_launch(void* const* d_in, const int* in_sizes, int n_in,
                              void* d_out, int out_size, void* d_ws, size_t ws_size,
                              hipStream_t stream) {
  const float* x  = (const float*)d_in[0];
  const float* y  = (const float*)d_in[1];
  const float* Wq = (const float*)d_in[2];
  const float* Wk = (const float*)d_in[3];
  const float* Wv = (const float*)d_in[4];
  const float* Wo = (const float*)d_in[5];
  const float* bo = (const float*)d_in[6];
  float* out = (float*)d_out;

  const int64_t nx = (int64_t)NBATCH * QLEN * EMBED;  // 8,388,608
  const int64_t ny = (int64_t)NBATCH * KLEN * EMBED;  // 16,777,216
  const int64_t nw = (int64_t)EMBED * EMBED;          // 262,144

  // ws layout (bf16): xb | yb | Wqb | Wkb | Wvb | Wob | Qm | Km | Vt  (~136MB)
  u16* w   = (u16*)d_ws;
  u16* xb  = w;            // dead after Q projection
  u16* O   = w; w += nx;   // attn output overlays xb
  u16* yb  = w; w += ny;
  u16* Wqb = w; w += nw;
  u16* Wkb = w; w += nw;
  u16* Wvb = w; w += nw;
  u16* Wob = w; w += nw;
  u16* Qm  = w; w += nx;
  u16* Km  = w; w += ny;
  u16* Vt  = w; w += ny;   // [8][512][4096]

  // one fused fp32->bf16 conversion over the contiguous region
  cvt_all_kernel<<<25600, 256, 0, stream>>>(x, y, Wq, Wk, Wv, Wo, xb);

  // Qm = (x@Wq^T) * 1/sqrt(512)
  const float scal = 0.04419417382415922f;
  gemm_bt<EPI_BF16_SCALE><<<dim3(128, 4, 1), 256, 0, stream>>>(
      xb, Wqb, Qm, 16384, EMBED, EMBED, 0, 0, 0, scal, nullptr, nullptr, nullptr);
  gemm_bt<EPI_BF16><<<dim3(256, 4, 1), 256, 0, stream>>>(
      yb, Wkb, Km, 32768, EMBED, EMBED, 0, 0, 0, 1.f, nullptr, nullptr, nullptr);
  gemm_bt<EPI_BF16_TRANS><<<dim3(256, 4, 1), 256, 0, stream>>>(
      yb, Wvb, nullptr, 32768, EMBED, EMBED, 0, 0, 0, 1.f, nullptr, nullptr, Vt);

  // fused attention (writes O over the dead xb slot)
  attn_kernel<<<NBATCH * 32, 256, 0, stream>>>(Qm, Km, Vt, O);

  // out = x + O @ Wo^T + bo   (fp32 epilogue)
  gemm_bt<EPI_F32_RESID><<<dim3(128, 4, 1), 256, 0, stream>>>(
      O, Wob, out, 16384, EMBED, EMBED, 0, 0, 0, 1.f, x, bo, nullptr);
}